// Round 1
// baseline (226.174 us; speedup 1.0000x reference)
//
#include <hip/hip_runtime.h>
#include <hip/hip_bf16.h>

typedef short s8v __attribute__((ext_vector_type(8)));
typedef float f4v __attribute__((ext_vector_type(4)));

#define MFMA16(A,B,C) __builtin_amdgcn_mfma_f32_16x16x32_bf16((A),(B),(C),0,0,0)

#define E_TOT 245760
#define N_TOT 98304
#define B_GR  8192

__device__ __forceinline__ unsigned short f2bf(float f) {
    unsigned u = __builtin_bit_cast(unsigned, f);
    u += 0x7fffu + ((u >> 16) & 1u);
    return (unsigned short)(u >> 16);
}

__device__ __forceinline__ void gload_lds16(const void* g, void* l) {
    __builtin_amdgcn_global_load_lds(
        (const __attribute__((address_space(1))) void*)g,
        (__attribute__((address_space(3))) void*)l, 16, 0, 0);
}

// ---------------------------------------------------------------- pack ----
// w1p : [12nt][64][8]            6144   bf16   (K 30->32 pad)
// w2p : [22c][2t][6s][64][8]     135168 bf16
// l1p : [6nt][12s][64][8]        36864  bf16
// l2p : [3nt][3s][64][8]         4608   bf16
// l3p : [9nt][2s][64][8]         9216   bf16   (K 48->64 pad, N 132->144 pad)
__global__ void pack_kernel(const float* __restrict__ w1, const float* __restrict__ w2,
                            const float* __restrict__ l1w, const float* __restrict__ l2w,
                            const float* __restrict__ l3w,
                            unsigned short* __restrict__ w1p, unsigned short* __restrict__ w2p,
                            unsigned short* __restrict__ l1p, unsigned short* __restrict__ l2p,
                            unsigned short* __restrict__ l3p)
{
    int idx = blockIdx.x * 256 + threadIdx.x;
    if (idx >= 192000) return;
    if (idx < 6144) {
        int i = idx & 7, l = (idx >> 3) & 63, nt = idx >> 9;
        int k = (l >> 4) * 8 + i, col = nt * 16 + (l & 15);
        w1p[idx] = f2bf(k < 30 ? w1[k * 192 + col] : 0.f);
    } else if (idx < 141312) {
        int e = idx - 6144;
        int i = e & 7, l = (e >> 3) & 63, rest = e >> 9;
        int s = rest % 6, ct = rest / 6, t = ct & 1, c = ct >> 1;
        int k = s * 32 + (l >> 4) * 8 + i, j = c * 32 + t * 16 + (l & 15);
        w2p[e] = f2bf(w2[k * 704 + j]);
    } else if (idx < 178176) {
        int e = idx - 141312;
        int i = e & 7, l = (e >> 3) & 63, rest = e >> 9;
        int s = rest % 12, nt = rest / 12;
        int k = s * 32 + (l >> 4) * 8 + i, j = nt * 16 + (l & 15);
        l1p[e] = f2bf(l1w[k * 96 + j]);
    } else if (idx < 182784) {
        int e = idx - 178176;
        int i = e & 7, l = (e >> 3) & 63, rest = e >> 9;
        int s = rest % 3, nt = rest / 3;
        int k = s * 32 + (l >> 4) * 8 + i, j = nt * 16 + (l & 15);
        l2p[e] = f2bf(l2w[k * 48 + j]);
    } else {
        int e = idx - 182784;
        int i = e & 7, l = (e >> 3) & 63, rest = e >> 9;
        int s = rest & 1, nt = rest >> 1;
        int k = s * 32 + (l >> 4) * 8 + i, j = nt * 16 + (l & 15);
        l3p[e] = f2bf((k < 48 && j < 132) ? l3w[k * 132 + j] : 0.f);
    }
}

// ------------------------------------------------------- fused edge path ----
// block = 256 (4 waves), 48 edges/wave, 192 edges/block, grid 1280
__launch_bounds__(256, 2)
__global__ void edge_kernel(const float* __restrict__ x,
                            const float* __restrict__ ea,
                            const int*   __restrict__ eidx,
                            const unsigned short* __restrict__ w1p,
                            const unsigned short* __restrict__ w2p,
                            const float* __restrict__ b1,
                            const float* __restrict__ b2,
                            float* __restrict__ agg)
{
    __shared__ __align__(16) unsigned short w2cl[6144];          // 12288 B
    __shared__ __align__(16) unsigned short hscr[4][16][200];    // 25600 B (pad stride 400B)
    __shared__ float xs[192][22];                                // 16896 B
    __shared__ float b2l[704];                                   // 2816 B
    __shared__ int   dstl[192];                                  // 768 B

    const int tid  = threadIdx.x;
    const int wave = tid >> 6, lane = tid & 63;
    const int hi = lane >> 4, col = lane & 15;
    const int e0 = blockIdx.x * 192;

    // stage gathered source features, dst indices, b2
    for (int idx = tid; idx < 192 * 22; idx += 256) {
        int e = idx / 22, c = idx - e * 22;
        int s = eidx[e0 + e];
        xs[e][c] = x[s * 22 + c];
    }
    for (int idx = tid; idx < 192; idx += 256) dstl[idx] = eidx[E_TOT + e0 + idx];
    for (int idx = tid; idx < 704; idx += 256) b2l[idx] = b2[idx];

    // ---- layer 1: h = relu(ea @ w1 + b1), per-wave 48 edges -> A-frags ----
    s8v w1f[12];
#pragma unroll
    for (int nt = 0; nt < 12; ++nt) w1f[nt] = *(const s8v*)(w1p + (nt * 64 + lane) * 8);
    float b1v[12];
#pragma unroll
    for (int nt = 0; nt < 12; ++nt) b1v[nt] = b1[nt * 16 + col];

    s8v haf[3][6];
#pragma unroll
    for (int mt = 0; mt < 3; ++mt) {
        int er = e0 + wave * 48 + mt * 16 + col;
        s8v af;
#pragma unroll
        for (int i = 0; i < 8; ++i) {
            int k = hi * 8 + i;
            af[i] = (short)f2bf(k < 30 ? ea[er * 30 + k] : 0.f);
        }
        f4v hc[12];
#pragma unroll
        for (int nt = 0; nt < 12; ++nt) {
            f4v z = {0.f, 0.f, 0.f, 0.f};
            hc[nt] = MFMA16(af, w1f[nt], z);
        }
        __syncthreads();   // protect scratch reuse (prev mt reads done)
#pragma unroll
        for (int nt = 0; nt < 12; ++nt)
#pragma unroll
            for (int r = 0; r < 4; ++r) {
                float v = hc[nt][r] + b1v[nt];
                v = v > 0.f ? v : 0.f;
                hscr[wave][hi * 4 + r][nt * 16 + col] = f2bf(v);
            }
        __syncthreads();   // scratch visible
#pragma unroll
        for (int s = 0; s < 6; ++s)
            haf[mt][s] = *(const s8v*)&hscr[wave][col][s * 32 + hi * 8];
    }

    // ---- layer 2 + einsum, c-loop over 22 feature channels ----
    f4v msg[3][2];
#pragma unroll
    for (int mt = 0; mt < 3; ++mt)
#pragma unroll
        for (int t = 0; t < 2; ++t) msg[mt][t] = (f4v){0.f, 0.f, 0.f, 0.f};

    for (int c = 0; c < 22; ++c) {
        __syncthreads();   // w2cl free
#pragma unroll
        for (int r = 0; r < 3; ++r) {
            const unsigned short* g = w2p + c * 6144 + (r * 256 + tid) * 8;
            unsigned short* l = &w2cl[(r * 256 + wave * 64) * 8];   // wave-uniform base
            gload_lds16(g, l);
        }
        __syncthreads();   // w2cl ready (sync drains vmcnt)

        s8v bf[2][6];
#pragma unroll
        for (int t = 0; t < 2; ++t)
#pragma unroll
            for (int s = 0; s < 6; ++s)
                bf[t][s] = *(const s8v*)&w2cl[((t * 6 + s) * 64 + lane) * 8];

        f4v pacc[3][2];
#pragma unroll
        for (int mt = 0; mt < 3; ++mt)
#pragma unroll
            for (int t = 0; t < 2; ++t) {
                f4v a = {0.f, 0.f, 0.f, 0.f};
#pragma unroll
                for (int s = 0; s < 6; ++s) a = MFMA16(haf[mt][s], bf[t][s], a);
                pacc[mt][t] = a;
            }

        float b2v0 = b2l[c * 32 + col];
        float b2v1 = b2l[c * 32 + 16 + col];
#pragma unroll
        for (int mt = 0; mt < 3; ++mt)
#pragma unroll
            for (int r = 0; r < 4; ++r) {
                float xv = xs[wave * 48 + mt * 16 + hi * 4 + r][c];
                msg[mt][0][r] += xv * (pacc[mt][0][r] + b2v0);
                msg[mt][1][r] += xv * (pacc[mt][1][r] + b2v1);
            }
    }

    // ---- scatter-add to agg ----
#pragma unroll
    for (int mt = 0; mt < 3; ++mt)
#pragma unroll
        for (int r = 0; r < 4; ++r) {
            int e = wave * 48 + mt * 16 + hi * 4 + r;
            int d = dstl[e];
            atomicAdd(&agg[d * 32 + col],      msg[mt][0][r]);
            atomicAdd(&agg[d * 32 + 16 + col], msg[mt][1][r]);
        }
}

// ------------------------------------------------------------- node ----
// g = relu(x @ root1 + agg + bias1) -> bf16 [N,32] == [B,384]
__global__ void node_kernel(const float* __restrict__ x, const float* __restrict__ agg,
                            const float* __restrict__ root1, const float* __restrict__ bias1,
                            unsigned short* __restrict__ g2d)
{
    __shared__ float r1[704];
    int tid = threadIdx.x;
    for (int i = tid; i < 704; i += 256) r1[i] = root1[i];
    __syncthreads();
    int gid = blockIdx.x * 256 + tid;
    int n = gid >> 2, j0 = (gid & 3) * 8;
    float acc[8];
#pragma unroll
    for (int j = 0; j < 8; ++j) acc[j] = agg[n * 32 + j0 + j] + bias1[j0 + j];
    for (int c = 0; c < 22; ++c) {
        float xc = x[n * 22 + c];
#pragma unroll
        for (int j = 0; j < 8; ++j) acc[j] += xc * r1[c * 32 + j0 + j];
    }
    s8v v;
#pragma unroll
    for (int j = 0; j < 8; ++j) {
        float t = acc[j] > 0.f ? acc[j] : 0.f;
        v[j] = (short)f2bf(t);
    }
    *(s8v*)&g2d[n * 32 + j0] = v;
}

// ------------------------------------------------------------- head ----
__launch_bounds__(256)
__global__ void head1_kernel(const unsigned short* __restrict__ g2d,
                             const unsigned short* __restrict__ l1p,
                             const float* __restrict__ bias, unsigned short* __restrict__ a1)
{
    int tid = threadIdx.x, wave = tid >> 6, lane = tid & 63, hi = lane >> 4, col = lane & 15;
    int r0 = blockIdx.x * 128 + wave * 32;
    f4v acc[2][6];
#pragma unroll
    for (int m = 0; m < 2; ++m)
#pragma unroll
        for (int n = 0; n < 6; ++n) acc[m][n] = (f4v){0.f, 0.f, 0.f, 0.f};
    for (int s = 0; s < 12; ++s) {
        s8v a0 = *(const s8v*)&g2d[(r0 + col) * 384 + s * 32 + hi * 8];
        s8v a1f = *(const s8v*)&g2d[(r0 + 16 + col) * 384 + s * 32 + hi * 8];
#pragma unroll
        for (int nt = 0; nt < 6; ++nt) {
            s8v bfr = *(const s8v*)&l1p[((nt * 12 + s) * 64 + lane) * 8];
            acc[0][nt] = MFMA16(a0, bfr, acc[0][nt]);
            acc[1][nt] = MFMA16(a1f, bfr, acc[1][nt]);
        }
    }
#pragma unroll
    for (int nt = 0; nt < 6; ++nt) {
        float bv = bias[nt * 16 + col];
#pragma unroll
        for (int m = 0; m < 2; ++m)
#pragma unroll
            for (int r = 0; r < 4; ++r) {
                float v = acc[m][nt][r] + bv;
                v = v > 0.f ? v : 0.f;
                a1[(r0 + m * 16 + hi * 4 + r) * 96 + nt * 16 + col] = f2bf(v);
            }
    }
}

__launch_bounds__(256)
__global__ void head2_kernel(const unsigned short* __restrict__ a1,
                             const unsigned short* __restrict__ l2p,
                             const float* __restrict__ bias, unsigned short* __restrict__ a2)
{
    int tid = threadIdx.x, wave = tid >> 6, lane = tid & 63, hi = lane >> 4, col = lane & 15;
    int r0 = blockIdx.x * 128 + wave * 32;
    f4v acc[2][3];
#pragma unroll
    for (int m = 0; m < 2; ++m)
#pragma unroll
        for (int n = 0; n < 3; ++n) acc[m][n] = (f4v){0.f, 0.f, 0.f, 0.f};
#pragma unroll
    for (int s = 0; s < 3; ++s) {
        s8v a0 = *(const s8v*)&a1[(r0 + col) * 96 + s * 32 + hi * 8];
        s8v a1f = *(const s8v*)&a1[(r0 + 16 + col) * 96 + s * 32 + hi * 8];
#pragma unroll
        for (int nt = 0; nt < 3; ++nt) {
            s8v bfr = *(const s8v*)&l2p[((nt * 3 + s) * 64 + lane) * 8];
            acc[0][nt] = MFMA16(a0, bfr, acc[0][nt]);
            acc[1][nt] = MFMA16(a1f, bfr, acc[1][nt]);
        }
    }
#pragma unroll
    for (int nt = 0; nt < 3; ++nt) {
        float bv = bias[nt * 16 + col];
#pragma unroll
        for (int m = 0; m < 2; ++m)
#pragma unroll
            for (int r = 0; r < 4; ++r) {
                float v = acc[m][nt][r] + bv;
                v = v > 0.f ? v : 0.f;
                a2[(r0 + m * 16 + hi * 4 + r) * 48 + nt * 16 + col] = f2bf(v);
            }
    }
}

__launch_bounds__(256)
__global__ void head3_kernel(const unsigned short* __restrict__ a2,
                             const unsigned short* __restrict__ l3p,
                             const float* __restrict__ bias, float* __restrict__ out)
{
    int tid = threadIdx.x, wave = tid >> 6, lane = tid & 63, hi = lane >> 4, col = lane & 15;
    int r0 = blockIdx.x * 128 + wave * 32;
    f4v acc[2][9];
#pragma unroll
    for (int m = 0; m < 2; ++m)
#pragma unroll
        for (int n = 0; n < 9; ++n) acc[m][n] = (f4v){0.f, 0.f, 0.f, 0.f};
#pragma unroll
    for (int s = 0; s < 2; ++s) {
        s8v a0, a1f;
        if (s == 1 && hi >= 2) {     // K tail: k>=48 is zero-padded in B anyway
            a0 = (s8v)0; a1f = (s8v)0;
        } else {
            a0 = *(const s8v*)&a2[(r0 + col) * 48 + s * 32 + hi * 8];
            a1f = *(const s8v*)&a2[(r0 + 16 + col) * 48 + s * 32 + hi * 8];
        }
#pragma unroll
        for (int nt = 0; nt < 9; ++nt) {
            s8v bfr = *(const s8v*)&l3p[((nt * 2 + s) * 64 + lane) * 8];
            acc[0][nt] = MFMA16(a0, bfr, acc[0][nt]);
            acc[1][nt] = MFMA16(a1f, bfr, acc[1][nt]);
        }
    }
#pragma unroll
    for (int nt = 0; nt < 9; ++nt) {
        int oc = nt * 16 + col;
        if (oc < 132) {
            float bv = bias[oc];
#pragma unroll
            for (int m = 0; m < 2; ++m)
#pragma unroll
                for (int r = 0; r < 4; ++r) {
                    float v = acc[m][nt][r] + bv;
                    v = v > 0.f ? v : 0.f;
                    out[(r0 + m * 16 + hi * 4 + r) * 132 + oc] = v;
                }
        }
    }
}

// ---------------------------------------------------------------- launch ----
extern "C" void kernel_launch(void* const* d_in, const int* in_sizes, int n_in,
                              void* d_out, int out_size, void* d_ws, size_t ws_size,
                              hipStream_t stream)
{
    const float* x     = (const float*)d_in[0];
    const float* ea    = (const float*)d_in[1];
    const int*   ei    = (const int*)d_in[2];
    const float* w1    = (const float*)d_in[3];
    const float* b1    = (const float*)d_in[4];
    const float* w2    = (const float*)d_in[5];
    const float* b2    = (const float*)d_in[6];
    const float* root1 = (const float*)d_in[7];
    const float* bias1 = (const float*)d_in[8];
    const float* l1w   = (const float*)d_in[9];
    const float* l1b   = (const float*)d_in[10];
    const float* l2w   = (const float*)d_in[11];
    const float* l2b   = (const float*)d_in[12];
    const float* l3w   = (const float*)d_in[13];
    const float* l3b   = (const float*)d_in[14];
    float* out = (float*)d_out;

    char* ws = (char*)d_ws;
    unsigned short* w1p = (unsigned short*)(ws + 0);
    unsigned short* w2p = (unsigned short*)(ws + 12288);
    unsigned short* l1p = (unsigned short*)(ws + 282624);
    unsigned short* l2p = (unsigned short*)(ws + 356352);
    unsigned short* l3p = (unsigned short*)(ws + 365568);
    float*          agg = (float*)(ws + 384000);
    unsigned short* g2d = (unsigned short*)(ws + 12966912);
    unsigned short* a1  = (unsigned short*)(ws + 19258368);
    unsigned short* a2  = (unsigned short*)(ws + 20831232);

    hipMemsetAsync(agg, 0, (size_t)N_TOT * 32 * 4, stream);
    pack_kernel<<<750, 256, 0, stream>>>(w1, w2, l1w, l2w, l3w, w1p, w2p, l1p, l2p, l3p);
    edge_kernel<<<1280, 256, 0, stream>>>(x, ea, ei, w1p, w2p, b1, b2, agg);
    node_kernel<<<1536, 256, 0, stream>>>(x, agg, root1, bias1, g2d);
    head1_kernel<<<64, 256, 0, stream>>>(g2d, l1p, l1b, a1);
    head2_kernel<<<64, 256, 0, stream>>>(a1, l2p, l2b, a2);
    head3_kernel<<<64, 256, 0, stream>>>(a2, l3p, l3b, out);
}